// Round 2
// baseline (210.837 us; speedup 1.0000x reference)
//
#include <hip/hip_runtime.h>

#define BB 2
#define NN 16384
#define KK 4096
#define CC 128
#define SS 32

// ---------------------------------------------------------------------------
// Kernel 1: ball query. One wave (64 lanes) per query point.
// Scans n ascending in chunks of 64; appends in-ball indices in order via
// ballot + prefix popcount; early-exits once 32 found. Matches reference
// selection semantics exactly (smallest 32 indices, ascending, tail-filled
// with first index, or 0 if none).
// ---------------------------------------------------------------------------
__global__ __launch_bounds__(256) void ball_query_kernel(
    const float* __restrict__ xyz,       // [B][N][3]
    const float* __restrict__ new_xyz,   // [B][K][3]
    int* __restrict__ idx_buf)           // [B*K][S]
{
    const int wave = threadIdx.x >> 6;           // 0..3
    const int lane = threadIdx.x & 63;
    const int qi   = blockIdx.x * 4 + wave;      // 0..B*K-1
    const int b    = qi >> 12;                   // K = 4096 = 2^12
    const int k    = qi & (KK - 1);

    // Exactly the reference constant: double 0.4*0.4 cast to f32
    // (NOT 0.4f*0.4f, which is 1 ulp larger).
    const float R2 = (float)(0.4 * 0.4);

    const float* q = new_xyz + (size_t)(b * KK + k) * 3;
    const float qx = q[0], qy = q[1], qz = q[2];
    // qq = (qx*qx + qy*qy) + qz*qz, no fma contraction
    const float qq = __fadd_rn(__fadd_rn(__fmul_rn(qx, qx), __fmul_rn(qy, qy)),
                               __fmul_rn(qz, qz));

    const float* xb = xyz + (size_t)b * NN * 3;
    int* out = idx_buf + (size_t)qi * SS;

    int cnt = 0;
    int first = -1;

    for (int base = 0; base < NN && cnt < SS; base += 64) {
        const int n = base + lane;               // N % 64 == 0, always valid
        const float* p = xb + (size_t)n * 3;
        const float px = p[0], py = p[1], pz = p[2];
        const float pp  = __fadd_rn(__fadd_rn(__fmul_rn(px, px), __fmul_rn(py, py)),
                                    __fmul_rn(pz, pz));
        const float dot = __fadd_rn(__fadd_rn(__fmul_rn(qx, px), __fmul_rn(qy, py)),
                                    __fmul_rn(qz, pz));
        // d2 = (qq + pp) - 2*dot  -- same association as the reference
        const float d2 = __fsub_rn(__fadd_rn(qq, pp), __fmul_rn(2.0f, dot));
        const bool inball = d2 < R2;

        const unsigned long long mask = __ballot(inball);
        if (first < 0 && mask)
            first = base + (int)__builtin_ctzll(mask);
        if (inball) {
            const int pos = cnt + __popcll(mask & ((1ull << lane) - 1ull));
            if (pos < SS) out[pos] = n;
        }
        cnt += __popcll(mask);
    }

    // Tail fill: slots >= cnt get the first in-ball index (0 if none).
    const int fill = (first < 0) ? 0 : first;
    if (lane < SS && lane >= cnt) out[lane] = fill;
}

// ---------------------------------------------------------------------------
// Kernel 2: grouping. Each thread owns 4 samples of one k; loops 32 channels
// (grid.y = 4 splits C). float4 coalesced writes; scalar gather reads.
// grid.y == 0 blocks also emit the (small) grouped_xyz output.
// ---------------------------------------------------------------------------
__global__ __launch_bounds__(256) void group_kernel(
    const float* __restrict__ xyz,       // [B][N][3]
    const float* __restrict__ new_xyz,   // [B][K][3]
    const float* __restrict__ feat,      // [B][C][N]
    const int*   __restrict__ idx_buf,   // [B*K][S]
    float* __restrict__ out)             // [B][3][K][S] ++ [B][C][K][S]
{
    const int t  = threadIdx.x;
    const int sq = t & 7;                // 8 sample-quads
    const int kk = t >> 3;               // 32 k's per block
    const int bk = blockIdx.x * 32 + kk; // global b*K + k
    const int b  = bk >> 12;
    const int k  = bk & (KK - 1);
    const int s0 = sq * 4;

    const int4 idx4 = *(const int4*)(idx_buf + (size_t)bk * SS + s0);

    float* out_xyz  = out;
    float* out_feat = out + (size_t)BB * 3 * KK * SS;

    const float* fb = feat + (size_t)b * CC * NN;
    const int c0 = blockIdx.y * 32;

#pragma unroll 4
    for (int c = c0; c < c0 + 32; ++c) {
        const float* row = fb + (size_t)c * NN;
        float4 v;
        v.x = row[idx4.x];
        v.y = row[idx4.y];
        v.z = row[idx4.z];
        v.w = row[idx4.w];
        *(float4*)(out_feat + (((size_t)(b * CC + c) * KK + k) * SS + s0)) = v;
    }

    if (blockIdx.y == 0) {
        const float* xb = xyz + (size_t)b * NN * 3;
        const float* q  = new_xyz + (size_t)(b * KK + k) * 3;
#pragma unroll
        for (int d = 0; d < 3; ++d) {
            const float qd = q[d];
            float4 v;
            v.x = (xb[(size_t)idx4.x * 3 + d] - qd) / 0.4f;
            v.y = (xb[(size_t)idx4.y * 3 + d] - qd) / 0.4f;
            v.z = (xb[(size_t)idx4.z * 3 + d] - qd) / 0.4f;
            v.w = (xb[(size_t)idx4.w * 3 + d] - qd) / 0.4f;
            *(float4*)(out_xyz + (((size_t)(b * 3 + d) * KK + k) * SS + s0)) = v;
        }
    }
}

extern "C" void kernel_launch(void* const* d_in, const int* in_sizes, int n_in,
                              void* d_out, int out_size, void* d_ws, size_t ws_size,
                              hipStream_t stream) {
    const float* xyz     = (const float*)d_in[0];   // [2][16384][3]
    const float* new_xyz = (const float*)d_in[1];   // [2][4096][3]
    const float* feat    = (const float*)d_in[2];   // [2][128][16384]
    float* out = (float*)d_out;
    int* idx_buf = (int*)d_ws;                      // B*K*S ints = 1 MB

    // Kernel 1: 8192 queries, 4 waves/block -> 2048 blocks
    ball_query_kernel<<<dim3(BB * KK / 4), dim3(256), 0, stream>>>(
        xyz, new_xyz, idx_buf);

    // Kernel 2: grid (B*K/32, C/32) = (256, 4), 256 threads
    group_kernel<<<dim3(BB * KK / 32, CC / 32), dim3(256), 0, stream>>>(
        xyz, new_xyz, feat, idx_buf, out);
}

// Round 4
// 169.291 us; speedup vs baseline: 1.2454x; 1.2454x over previous
//
#include <hip/hip_runtime.h>

#define BB 2
#define NN 16384
#define KK 4096
#define CC 128
#define SS 32

// Native clang vector type — required by __builtin_nontemporal_store
// (HIP's float4 is a class and is rejected).
typedef float vfloat4 __attribute__((ext_vector_type(4)));

// ---------------------------------------------------------------------------
// Kernel 1: ball query. One wave per query; scans n ascending in 128-point
// iterations (2x64) with a one-iteration register prefetch to hide L2 latency
// in the full-scan tail. Selection semantics identical to reference.
// Arithmetic EXACTLY matches reference (no fma, left-assoc, R2=(f32)(0.4*0.4))
// -> absmax 0.0 verified in round 2. Do not alter the float expressions.
// ---------------------------------------------------------------------------
__global__ __launch_bounds__(256) void ball_query_kernel(
    const float* __restrict__ xyz,       // [B][N][3]
    const float* __restrict__ new_xyz,   // [B][K][3]
    int* __restrict__ idx_buf)           // [B*K][S]
{
    const int wave = threadIdx.x >> 6;
    const int lane = threadIdx.x & 63;
    const int qi   = blockIdx.x * 4 + wave;
    const int b    = qi >> 12;                   // K = 4096
    const int k    = qi & (KK - 1);

    const float R2 = (float)(0.4 * 0.4);

    const float* q = new_xyz + (size_t)(b * KK + k) * 3;
    const float qx = q[0], qy = q[1], qz = q[2];
    const float qq = __fadd_rn(__fadd_rn(__fmul_rn(qx, qx), __fmul_rn(qy, qy)),
                               __fmul_rn(qz, qz));

    const float* xb = xyz + (size_t)b * NN * 3;
    int* out = idx_buf + (size_t)qi * SS;

    int cnt = 0;
    int first = -1;

    auto load3 = [&](int n, float& x, float& y, float& z) {
        const float* p = xb + (size_t)n * 3;
        x = p[0]; y = p[1]; z = p[2];
    };

    auto process = [&](int base, float px, float py, float pz) {
        const float pp  = __fadd_rn(__fadd_rn(__fmul_rn(px, px), __fmul_rn(py, py)),
                                    __fmul_rn(pz, pz));
        const float dot = __fadd_rn(__fadd_rn(__fmul_rn(qx, px), __fmul_rn(qy, py)),
                                    __fmul_rn(qz, pz));
        const float d2 = __fsub_rn(__fadd_rn(qq, pp), __fmul_rn(2.0f, dot));
        const bool inball = d2 < R2;
        const unsigned long long mask = __ballot(inball);
        if (first < 0 && mask)
            first = base + (int)__builtin_ctzll(mask);
        if (inball) {
            const int pos = cnt + __popcll(mask & ((1ull << lane) - 1ull));
            if (pos < SS) out[pos] = base + lane;
        }
        cnt += __popcll(mask);
    };

    // 2-subchunk iteration with 1-iteration register prefetch.
    float ax, ay, az, bx, by, bz;
    load3(lane, ax, ay, az);
    load3(64 + lane, bx, by, bz);

    for (int base = 0; base < NN; base += 128) {
        const int nb = (base + 128 < NN) ? base + 128 : 0;  // clamp: values unused
        float cx, cy, cz, dx, dy, dz;
        load3(nb + lane, cx, cy, cz);
        load3(nb + 64 + lane, dx, dy, dz);

        process(base, ax, ay, az);
        process(base + 64, bx, by, bz);
        if (cnt >= SS) break;

        ax = cx; ay = cy; az = cz;
        bx = dx; by = dy; bz = dz;
    }

    const int fill = (first < 0) ? 0 : first;
    if (lane < SS && lane >= cnt) out[lane] = fill;
}

// ---------------------------------------------------------------------------
// Kernel 2: grouping. grid = (B*K/32, C/8): 4096 blocks, 16384 waves for full
// occupancy / max memory-level parallelism on the divergent scalar gathers.
// Nontemporal float4 stores keep the 134 MB output stream out of L2 so the
// 16.8 MB feature table stays resident for the gathers.
// ---------------------------------------------------------------------------
__global__ __launch_bounds__(256) void group_kernel(
    const float* __restrict__ xyz,       // [B][N][3]
    const float* __restrict__ new_xyz,   // [B][K][3]
    const float* __restrict__ feat,      // [B][C][N]
    const int*   __restrict__ idx_buf,   // [B*K][S]
    float* __restrict__ out)             // [B][3][K][S] ++ [B][C][K][S]
{
    const int t  = threadIdx.x;
    const int sq = t & 7;                // 8 sample-quads
    const int kk = t >> 3;               // 32 k's per block
    const int bk = blockIdx.x * 32 + kk;
    const int b  = bk >> 12;
    const int k  = bk & (KK - 1);
    const int s0 = sq * 4;

    const int4 idx4 = *(const int4*)(idx_buf + (size_t)bk * SS + s0);

    float* out_xyz  = out;
    float* out_feat = out + (size_t)BB * 3 * KK * SS;

    const float* fb = feat + (size_t)b * CC * NN;
    const int c0 = blockIdx.y * 8;

#pragma unroll
    for (int c = c0; c < c0 + 8; ++c) {
        const float* row = fb + (size_t)c * NN;
        vfloat4 v;
        v.x = row[idx4.x];
        v.y = row[idx4.y];
        v.z = row[idx4.z];
        v.w = row[idx4.w];
        __builtin_nontemporal_store(
            v, (vfloat4*)(out_feat + (((size_t)(b * CC + c) * KK + k) * SS + s0)));
    }

    if (blockIdx.y == 0) {
        const float* xb = xyz + (size_t)b * NN * 3;
        const float* q  = new_xyz + (size_t)(b * KK + k) * 3;
#pragma unroll
        for (int d = 0; d < 3; ++d) {
            const float qd = q[d];
            vfloat4 v;
            v.x = (xb[(size_t)idx4.x * 3 + d] - qd) / 0.4f;
            v.y = (xb[(size_t)idx4.y * 3 + d] - qd) / 0.4f;
            v.z = (xb[(size_t)idx4.z * 3 + d] - qd) / 0.4f;
            v.w = (xb[(size_t)idx4.w * 3 + d] - qd) / 0.4f;
            __builtin_nontemporal_store(
                v, (vfloat4*)(out_xyz + (((size_t)(b * 3 + d) * KK + k) * SS + s0)));
        }
    }
}

extern "C" void kernel_launch(void* const* d_in, const int* in_sizes, int n_in,
                              void* d_out, int out_size, void* d_ws, size_t ws_size,
                              hipStream_t stream) {
    const float* xyz     = (const float*)d_in[0];   // [2][16384][3]
    const float* new_xyz = (const float*)d_in[1];   // [2][4096][3]
    const float* feat    = (const float*)d_in[2];   // [2][128][16384]
    float* out = (float*)d_out;
    int* idx_buf = (int*)d_ws;                      // B*K*S ints = 1 MB

    ball_query_kernel<<<dim3(BB * KK / 4), dim3(256), 0, stream>>>(
        xyz, new_xyz, idx_buf);

    group_kernel<<<dim3(BB * KK / 32, CC / 8), dim3(256), 0, stream>>>(
        xyz, new_xyz, feat, idx_buf, out);
}

// Round 6
// 91.100 us; speedup vs baseline: 2.3143x; 1.8583x over previous
//
#include <hip/hip_runtime.h>

#define BB 2
#define NN 16384
#define KK 4096
#define CC 128
#define SS 32

typedef float vfloat4 __attribute__((ext_vector_type(4)));

// ---------------------------------------------------------------------------
// Kernel A: build xyzw[b][n] = {x, y, z, |p|^2}. pp uses the EXACT reference
// expression (no fma, left-assoc) -> bit-identical to inline computation.
// ---------------------------------------------------------------------------
__global__ __launch_bounds__(256) void prep_xyzw_kernel(
    const float* __restrict__ xyz, float* __restrict__ xyzw)
{
    const int i = blockIdx.x * 256 + threadIdx.x;        // 0 .. BB*NN-1
    const float* p = xyz + (size_t)i * 3;
    const float x = p[0], y = p[1], z = p[2];
    const float pp = __fadd_rn(__fadd_rn(__fmul_rn(x, x), __fmul_rn(y, y)),
                               __fmul_rn(z, z));
    vfloat4 v = {x, y, z, pp};
    *(vfloat4*)(xyzw + (size_t)i * 4) = v;
}

// ---------------------------------------------------------------------------
// Kernel B: transpose features [B][C][N] -> [B][N][C] so a sample's channels
// are one contiguous 512B row. LDS tile 64n x 128c, pad 133 (bank-conflict-
// free: 5*ln mod 32 is a permutation within each 32-lane half).
// ---------------------------------------------------------------------------
__global__ __launch_bounds__(256) void transpose_kernel(
    const float* __restrict__ feat, float* __restrict__ feat_t)
{
    __shared__ float tile[64][133];
    const int b  = blockIdx.x >> 8;          // NN/64 = 256 tiles per batch
    const int n0 = (blockIdx.x & 255) * 64;
    const int t  = threadIdx.x;

    const int ln = t & 63;
    const int cr = t >> 6;                   // 0..3
#pragma unroll
    for (int p = 0; p < 32; ++p) {
        const int c = p * 4 + cr;
        tile[ln][c] = feat[((size_t)b * CC + c) * NN + n0 + ln];
    }
    __syncthreads();

    const int cl = t & 31;
    const int ns = t >> 5;                   // 0..7
#pragma unroll
    for (int p = 0; p < 8; ++p) {
        const int n = ns + 8 * p;
        float* dst = feat_t + ((size_t)(b * NN + n0 + n)) * CC;
#pragma unroll
        for (int j = 0; j < 4; ++j)
            dst[cl + 32 * j] = tile[n][cl + 32 * j];
    }
}

// ---------------------------------------------------------------------------
// Kernel C: ball query. One wave per query; 128-pt iterations with 1-iter
// register prefetch; xyzw gives one dwordx4/point; store path skipped when
// the chunk has no hits (common in the full-scan tail).
// Float exprs EXACTLY match reference (absmax 0.0 verified round 2/4).
// ---------------------------------------------------------------------------
__global__ __launch_bounds__(256) void ball_query_kernel(
    const float* __restrict__ xyzw,      // [B][N][4]
    const float* __restrict__ new_xyz,   // [B][K][3]
    int* __restrict__ idx_buf)           // [B*K][S]
{
    const int wave = threadIdx.x >> 6;
    const int lane = threadIdx.x & 63;
    const int qi   = blockIdx.x * 4 + wave;
    const int b    = qi >> 12;                   // K = 4096
    const int k    = qi & (KK - 1);

    const float R2 = (float)(0.4 * 0.4);

    const float* q = new_xyz + (size_t)(b * KK + k) * 3;
    const float qx = q[0], qy = q[1], qz = q[2];
    const float qq = __fadd_rn(__fadd_rn(__fmul_rn(qx, qx), __fmul_rn(qy, qy)),
                               __fmul_rn(qz, qz));

    const vfloat4* xw = (const vfloat4*)xyzw + (size_t)b * NN;
    int* out = idx_buf + (size_t)qi * SS;

    int cnt = 0;
    int first = -1;

    auto process = [&](int base, vfloat4 v) {
        const float dot = __fadd_rn(__fadd_rn(__fmul_rn(qx, v.x), __fmul_rn(qy, v.y)),
                                    __fmul_rn(qz, v.z));
        const float d2 = __fsub_rn(__fadd_rn(qq, v.w), __fmul_rn(2.0f, dot));
        const bool inball = d2 < R2;
        const unsigned long long mask = __ballot(inball);
        if (mask) {
            if (first < 0) first = base + (int)__builtin_ctzll(mask);
            if (inball) {
                const int pos = cnt + __popcll(mask & ((1ull << lane) - 1ull));
                if (pos < SS) out[pos] = base + lane;
            }
            cnt += __popcll(mask);
        }
    };

    vfloat4 va = xw[lane];
    vfloat4 vb = xw[64 + lane];

    for (int base = 0; base < NN; base += 128) {
        const int nb = (base + 128 < NN) ? base + 128 : 0;   // clamp; unused vals
        vfloat4 vc = xw[nb + lane];
        vfloat4 vd = xw[nb + 64 + lane];

        process(base, va);
        process(base + 64, vb);
        if (cnt >= SS) break;

        va = vc;
        vb = vd;
    }

    const int fill = (first < 0) ? 0 : first;
    if (lane < SS && lane >= cnt) out[lane] = fill;
}

// ---------------------------------------------------------------------------
// Kernel D: grouping from transposed features. One block per (b,k):
//   gather 32 samples x 512B contiguous -> LDS [32][132] -> coalesced
//   nontemporal float4 writes of [C][S]. 17 KB LDS, 8 blocks/CU.
// ---------------------------------------------------------------------------
__global__ __launch_bounds__(256) void group_kernel(
    const float* __restrict__ xyzw,      // [B][N][4]
    const float* __restrict__ new_xyz,   // [B][K][3]
    const float* __restrict__ feat_t,    // [B][N][C]
    const int*   __restrict__ idx_buf,   // [B*K][S]
    float* __restrict__ out)             // [B][3][K][S] ++ [B][C][K][S]
{
    __shared__ int   lidx[SS];
    __shared__ float tile[SS][132];
    __shared__ float txyz[3][SS];

    const int t  = threadIdx.x;
    const int bk = blockIdx.x;
    const int b  = bk >> 12;
    const int k  = bk & (KK - 1);

    if (t < SS) lidx[t] = idx_buf[(size_t)bk * SS + t];
    __syncthreads();

    // Gather: 32 lanes cover one sample's 128 channels (4 float4/lane-group).
    const int cl = t & 31;
    const int sg = t >> 5;                       // 0..7
#pragma unroll
    for (int p = 0; p < 4; ++p) {
        const int s = sg + 8 * p;
        const int n = lidx[s];
        const vfloat4 v = *(const vfloat4*)(feat_t + ((size_t)(b * NN + n)) * CC + 4 * cl);
        *(vfloat4*)&tile[s][4 * cl] = v;
    }

    // grouped_xyz (tiny): 32 threads, one sample each.
    if (t < SS) {
        const float* q = new_xyz + (size_t)bk * 3;
        const vfloat4 w = *((const vfloat4*)xyzw + (size_t)b * NN + lidx[t]);
        txyz[0][t] = (w.x - q[0]) / 0.4f;
        txyz[1][t] = (w.y - q[1]) / 0.4f;
        txyz[2][t] = (w.z - q[2]) / 0.4f;
    }
    __syncthreads();

    float* out_xyz  = out;
    float* out_feat = out + (size_t)BB * 3 * KK * SS;

    // Write [C][S]: lanes 0..7 = 8 s-quads of one channel (128B contiguous).
    const int sq = t & 7;
    const int c0 = t >> 3;                       // 0..31
#pragma unroll
    for (int p = 0; p < 4; ++p) {
        const int c = c0 + 32 * p;
        vfloat4 v;
        v.x = tile[4 * sq + 0][c];
        v.y = tile[4 * sq + 1][c];
        v.z = tile[4 * sq + 2][c];
        v.w = tile[4 * sq + 3][c];
        __builtin_nontemporal_store(
            v, (vfloat4*)(out_feat + (((size_t)(b * CC + c) * KK + k) * SS + 4 * sq)));
    }

    if (t < 24) {
        const int d   = t >> 3;
        const int sq2 = t & 7;
        const vfloat4 v = *(vfloat4*)&txyz[d][4 * sq2];
        __builtin_nontemporal_store(
            v, (vfloat4*)(out_xyz + (((size_t)(b * 3 + d) * KK + k) * SS + 4 * sq2)));
    }
}

extern "C" void kernel_launch(void* const* d_in, const int* in_sizes, int n_in,
                              void* d_out, int out_size, void* d_ws, size_t ws_size,
                              hipStream_t stream) {
    const float* xyz     = (const float*)d_in[0];   // [2][16384][3]
    const float* new_xyz = (const float*)d_in[1];   // [2][4096][3]
    const float* feat    = (const float*)d_in[2];   // [2][128][16384]
    float* out = (float*)d_out;

    // Workspace layout (18.3 MB total):
    int*   idx_buf = (int*)d_ws;                                  // 1 MB
    float* xyzw    = (float*)((char*)d_ws + (1 << 20));           // 512 KB
    float* feat_t  = (float*)((char*)d_ws + (1 << 20) + (512 << 10)); // 16 MB

    prep_xyzw_kernel<<<dim3(BB * NN / 256), dim3(256), 0, stream>>>(xyz, xyzw);

    transpose_kernel<<<dim3(BB * (NN / 64)), dim3(256), 0, stream>>>(feat, feat_t);

    ball_query_kernel<<<dim3(BB * KK / 4), dim3(256), 0, stream>>>(
        xyzw, new_xyz, idx_buf);

    group_kernel<<<dim3(BB * KK), dim3(256), 0, stream>>>(
        xyzw, new_xyz, feat_t, idx_buf, out);
}

// Round 7
// 90.787 us; speedup vs baseline: 2.3223x; 1.0034x over previous
//
#include <hip/hip_runtime.h>

#define BB 2
#define NN 16384
#define KK 4096
#define CC 128
#define SS 32

typedef float vfloat4 __attribute__((ext_vector_type(4)));

// ---------------------------------------------------------------------------
// Kernel A: transpose features [B][C][N] -> [B][N][C] (512B contiguous rows),
// PLUS fused xyzw prep: xyzw[b][n] = {x,y,z,|p|^2}. pp uses the EXACT
// reference expression (no fma, left-assoc) -> bit-identical (absmax 0.0
// verified rounds 2/4/6).
// ---------------------------------------------------------------------------
__global__ __launch_bounds__(256) void transpose_prep_kernel(
    const float* __restrict__ feat, const float* __restrict__ xyz,
    float* __restrict__ feat_t, float* __restrict__ xyzw)
{
    __shared__ float tile[64][133];
    const int b  = blockIdx.x >> 8;          // NN/64 = 256 tiles per batch
    const int n0 = (blockIdx.x & 255) * 64;
    const int t  = threadIdx.x;

    // Fused prep: first 64 threads handle this block's 64 points.
    if (t < 64) {
        const int i = b * NN + n0 + t;
        const float* p = xyz + (size_t)i * 3;
        const float x = p[0], y = p[1], z = p[2];
        const float pp = __fadd_rn(__fadd_rn(__fmul_rn(x, x), __fmul_rn(y, y)),
                                   __fmul_rn(z, z));
        vfloat4 v = {x, y, z, pp};
        *(vfloat4*)(xyzw + (size_t)i * 4) = v;
    }

    const int ln = t & 63;
    const int cr = t >> 6;                   // 0..3
#pragma unroll
    for (int p = 0; p < 32; ++p) {
        const int c = p * 4 + cr;
        tile[ln][c] = feat[((size_t)b * CC + c) * NN + n0 + ln];
    }
    __syncthreads();

    const int cl = t & 31;
    const int ns = t >> 5;                   // 0..7
#pragma unroll
    for (int p = 0; p < 8; ++p) {
        const int n = ns + 8 * p;
        float* dst = feat_t + ((size_t)(b * NN + n0 + n)) * CC;
#pragma unroll
        for (int j = 0; j < 4; ++j)
            dst[cl + 32 * j] = tile[n][cl + 32 * j];
    }
}

// ---------------------------------------------------------------------------
// Kernel B: ball query. One wave per query; 256-pt iterations (4x64) with a
// FULL next-iteration register prefetch (8 dwordx4 in flight) to hide L2
// latency in the full-scan tail. Selection semantics identical to reference.
// Float exprs EXACTLY match reference -> absmax 0.0. Do not alter.
// ---------------------------------------------------------------------------
__global__ __launch_bounds__(256) void ball_query_kernel(
    const float* __restrict__ xyzw,      // [B][N][4]
    const float* __restrict__ new_xyz,   // [B][K][3]
    int* __restrict__ idx_buf)           // [B*K][S]
{
    const int wave = threadIdx.x >> 6;
    const int lane = threadIdx.x & 63;
    const int qi   = blockIdx.x * 4 + wave;
    const int b    = qi >> 12;                   // K = 4096
    const int k    = qi & (KK - 1);

    const float R2 = (float)(0.4 * 0.4);

    const float* q = new_xyz + (size_t)(b * KK + k) * 3;
    const float qx = q[0], qy = q[1], qz = q[2];
    const float qq = __fadd_rn(__fadd_rn(__fmul_rn(qx, qx), __fmul_rn(qy, qy)),
                               __fmul_rn(qz, qz));

    const vfloat4* xw = (const vfloat4*)xyzw + (size_t)b * NN;
    int* out = idx_buf + (size_t)qi * SS;

    int cnt = 0;
    int first = -1;

    auto process = [&](int base, vfloat4 v) {
        const float dot = __fadd_rn(__fadd_rn(__fmul_rn(qx, v.x), __fmul_rn(qy, v.y)),
                                    __fmul_rn(qz, v.z));
        const float d2 = __fsub_rn(__fadd_rn(qq, v.w), __fmul_rn(2.0f, dot));
        const bool inball = d2 < R2;
        const unsigned long long mask = __ballot(inball);
        if (mask) {
            if (first < 0) first = base + (int)__builtin_ctzll(mask);
            if (inball) {
                const int pos = cnt + __popcll(mask & ((1ull << lane) - 1ull));
                if (pos < SS) out[pos] = base + lane;
            }
            cnt += __popcll(mask);
        }
    };

    vfloat4 v0 = xw[lane];
    vfloat4 v1 = xw[64 + lane];
    vfloat4 v2 = xw[128 + lane];
    vfloat4 v3 = xw[192 + lane];

    for (int base = 0; base < NN; base += 256) {
        const int nb = (base + 256 < NN) ? base + 256 : 0;   // clamp; unused vals
        vfloat4 u0 = xw[nb + lane];
        vfloat4 u1 = xw[nb + 64 + lane];
        vfloat4 u2 = xw[nb + 128 + lane];
        vfloat4 u3 = xw[nb + 192 + lane];

        process(base, v0);
        process(base + 64, v1);
        process(base + 128, v2);
        process(base + 192, v3);
        if (cnt >= SS) break;

        v0 = u0; v1 = u1; v2 = u2; v3 = u3;
    }

    const int fill = (first < 0) ? 0 : first;
    if (lane < SS && lane >= cnt) out[lane] = fill;
}

// ---------------------------------------------------------------------------
// Kernel C: grouping from transposed features. UNCHANGED from round 6
// (clean attribution). One block per (b,k): gather 32 samples x 512B
// contiguous -> LDS [32][132] -> coalesced nontemporal float4 [C][S] writes.
// ---------------------------------------------------------------------------
__global__ __launch_bounds__(256) void group_kernel(
    const float* __restrict__ xyzw,      // [B][N][4]
    const float* __restrict__ new_xyz,   // [B][K][3]
    const float* __restrict__ feat_t,    // [B][N][C]
    const int*   __restrict__ idx_buf,   // [B*K][S]
    float* __restrict__ out)             // [B][3][K][S] ++ [B][C][K][S]
{
    __shared__ int   lidx[SS];
    __shared__ float tile[SS][132];
    __shared__ float txyz[3][SS];

    const int t  = threadIdx.x;
    const int bk = blockIdx.x;
    const int b  = bk >> 12;
    const int k  = bk & (KK - 1);

    if (t < SS) lidx[t] = idx_buf[(size_t)bk * SS + t];
    __syncthreads();

    const int cl = t & 31;
    const int sg = t >> 5;                       // 0..7
#pragma unroll
    for (int p = 0; p < 4; ++p) {
        const int s = sg + 8 * p;
        const int n = lidx[s];
        const vfloat4 v = *(const vfloat4*)(feat_t + ((size_t)(b * NN + n)) * CC + 4 * cl);
        *(vfloat4*)&tile[s][4 * cl] = v;
    }

    if (t < SS) {
        const float* q = new_xyz + (size_t)bk * 3;
        const vfloat4 w = *((const vfloat4*)xyzw + (size_t)b * NN + lidx[t]);
        txyz[0][t] = (w.x - q[0]) / 0.4f;
        txyz[1][t] = (w.y - q[1]) / 0.4f;
        txyz[2][t] = (w.z - q[2]) / 0.4f;
    }
    __syncthreads();

    float* out_xyz  = out;
    float* out_feat = out + (size_t)BB * 3 * KK * SS;

    const int sq = t & 7;
    const int c0 = t >> 3;                       // 0..31
#pragma unroll
    for (int p = 0; p < 4; ++p) {
        const int c = c0 + 32 * p;
        vfloat4 v;
        v.x = tile[4 * sq + 0][c];
        v.y = tile[4 * sq + 1][c];
        v.z = tile[4 * sq + 2][c];
        v.w = tile[4 * sq + 3][c];
        __builtin_nontemporal_store(
            v, (vfloat4*)(out_feat + (((size_t)(b * CC + c) * KK + k) * SS + 4 * sq)));
    }

    if (t < 24) {
        const int d   = t >> 3;
        const int sq2 = t & 7;
        const vfloat4 v = *(vfloat4*)&txyz[d][4 * sq2];
        __builtin_nontemporal_store(
            v, (vfloat4*)(out_xyz + (((size_t)(b * 3 + d) * KK + k) * SS + 4 * sq2)));
    }
}

extern "C" void kernel_launch(void* const* d_in, const int* in_sizes, int n_in,
                              void* d_out, int out_size, void* d_ws, size_t ws_size,
                              hipStream_t stream) {
    const float* xyz     = (const float*)d_in[0];   // [2][16384][3]
    const float* new_xyz = (const float*)d_in[1];   // [2][4096][3]
    const float* feat    = (const float*)d_in[2];   // [2][128][16384]
    float* out = (float*)d_out;

    // Workspace layout (18.3 MB total):
    int*   idx_buf = (int*)d_ws;                                  // 1 MB
    float* xyzw    = (float*)((char*)d_ws + (1 << 20));           // 512 KB
    float* feat_t  = (float*)((char*)d_ws + (1 << 20) + (512 << 10)); // 16 MB

    transpose_prep_kernel<<<dim3(BB * (NN / 64)), dim3(256), 0, stream>>>(
        feat, xyz, feat_t, xyzw);

    ball_query_kernel<<<dim3(BB * KK / 4), dim3(256), 0, stream>>>(
        xyzw, new_xyz, idx_buf);

    group_kernel<<<dim3(BB * KK), dim3(256), 0, stream>>>(
        xyzw, new_xyz, feat_t, idx_buf, out);
}